// Round 15
// baseline (432.785 us; speedup 1.0000x reference)
//
#include <hip/hip_runtime.h>
#include <cstdint>

#define VDIM 10000
#define NROW 4096
#define DDIM 128
#define KTPAD 320           // kt steps padded (320*32 = 10240)
#define KSPLIT 8
#define SLABS_PER_CHUNK 5   // 5 slabs * 8 kt * 32 k = 1280 k per chunk
#define NCB 8               // 16-col blocks per kt tile

typedef __attribute__((ext_vector_type(8))) short bf16x8;
typedef __attribute__((ext_vector_type(4))) float f32x4;

__device__ __forceinline__ unsigned short f2bf(float f) {
    union { float f; unsigned u; } v; v.f = f;
    unsigned u = v.u;
    unsigned r = (u + 0x7FFFu + ((u >> 16) & 1u)) >> 16;  // RNE
    return (unsigned short)r;
}

__device__ __forceinline__ void pin4(const void* p) {
    const unsigned* u = (const unsigned*)p;
    asm volatile("" :: "v"(u[0]), "v"(u[1]), "v"(u[2]), "v"(u[3]));
}

// ---------------------------------------------------------------------------
// Kernel 1: build fragment-major B: embF[e][kt][cb][lane][8] bf16, kt < 320
// ---------------------------------------------------------------------------
__global__ __launch_bounds__(256) void build_embF(
    const float* __restrict__ ec, const float* __restrict__ er,
    unsigned short* __restrict__ embF)
{
    const int t = blockIdx.x * 256 + threadIdx.x;
    const int perE = KTPAD * NCB * 64;                 // 163840
    if (t >= 2 * perE) return;
    const int e    = t / perE;
    const int rem  = t - e * perE;
    const int kt   = rem >> 9;
    const int rem2 = rem & 511;
    const int cb   = rem2 >> 6;
    const int lane = rem2 & 63;
    const int col  = cb * 16 + (lane & 15);
    const int k0   = kt * 32 + (lane >> 4) * 8;

    unsigned short o[8];
    if (k0 + 8 <= VDIM) {
        const float* src = (e ? er : ec) + (size_t)col * VDIM + k0;
        #pragma unroll
        for (int j = 0; j < 8; ++j) o[j] = f2bf(src[j]);
    } else {
        #pragma unroll
        for (int j = 0; j < 8; ++j) o[j] = 0;
    }
    *reinterpret_cast<bf16x8*>(embF + (size_t)t * 8) =
        *reinterpret_cast<const bf16x8*>(o);
}

// ---------------------------------------------------------------------------
// Ablation GEMM. MODE: 0=full  2=B loads only  3=MFMA only  4=A glb loads only
// All modes share grid (64 rb x 3 s x 8 kc), block 256, same epilogue stores.
// Probes run BEFORE mode 0; mode 0 overwrites every reps8 element.
// ---------------------------------------------------------------------------
template<int MODE>
__global__ __launch_bounds__(256, 2) void gemm_abl(
    const float* __restrict__ a0, const float* __restrict__ a1,
    const float* __restrict__ a2,
    const unsigned short* __restrict__ embF,
    float* __restrict__ reps8)                // [8][3][4096][128] f32
{
    __shared__ short aLds[4][16][256];        // 32 KB, wave-private

    const int rb = blockIdx.x;
    const int s  = blockIdx.y;
    const int kc = blockIdx.z;
    const float* A = (s == 0) ? a0 : (s == 1 ? a1 : a2);
    const int e = (s == 0) ? 0 : 1;

    const int tid  = threadIdx.x;
    const int lane = tid & 63;
    const int w    = tid >> 6;
    const int l15  = lane & 15;
    const int quad = lane >> 4;

    const int slab0 = kc * SLABS_PER_CHUNK;
    const int rbase = rb * 64 + w * 16;
    const float* arow0 = A + (size_t)rbase * VDIM;
    const unsigned short* bbase =
        embF + (size_t)e * KTPAD * NCB * 512 + (size_t)lane * 8;

    f32x4 acc[8];
    #pragma unroll
    for (int ct = 0; ct < 8; ++ct) acc[ct] = (f32x4){0.f, 0.f, 0.f, 0.f};
    f32x4 sreg[16];

#define GLA(SL) do {                                                   \
        int f_ = (SL) * 256 + lane * 4;                                \
        f_ = f_ > (VDIM - 4) ? (VDIM - 4) : f_;                        \
        _Pragma("unroll")                                              \
        for (int j = 0; j < 16; ++j)                                   \
            sreg[j] = *reinterpret_cast<const f32x4*>(                 \
                arow0 + (size_t)j * VDIM + f_);                        \
    } while (0)

#define CVTWRITE() do {                                                \
        _Pragma("unroll")                                              \
        for (int j = 0; j < 16; ++j) {                                 \
            union { unsigned u[2]; } p_;                               \
            asm("v_cvt_pk_bf16_f32 %0, %1, %2"                         \
                : "=v"(p_.u[0]) : "v"(sreg[j][0]), "v"(sreg[j][1]));   \
            asm("v_cvt_pk_bf16_f32 %0, %1, %2"                         \
                : "=v"(p_.u[1]) : "v"(sreg[j][2]), "v"(sreg[j][3]));   \
            int col_ = (lane * 4) ^ ((j & 7) << 3);                    \
            *reinterpret_cast<uint2*>(&aLds[w][j][col_]) =             \
                *reinterpret_cast<const uint2*>(p_.u);                 \
        }                                                              \
    } while (0)

    // MODE 3: register-resident operands, loaded once
    bf16x8 afc{}, bqc0{}, bqc1{}, bqc2{}, bqc3{}, bqc4{}, bqc5{}, bqc6{}, bqc7{};
    if constexpr (MODE == 3) {
        afc  = *reinterpret_cast<const bf16x8*>(embF + (size_t)lane * 8);
        bqc0 = *reinterpret_cast<const bf16x8*>(bbase);
        bqc1 = *reinterpret_cast<const bf16x8*>(bbase + 512);
        bqc2 = *reinterpret_cast<const bf16x8*>(bbase + 1024);
        bqc3 = *reinterpret_cast<const bf16x8*>(bbase + 1536);
        bqc4 = *reinterpret_cast<const bf16x8*>(bbase + 2048);
        bqc5 = *reinterpret_cast<const bf16x8*>(bbase + 2560);
        bqc6 = *reinterpret_cast<const bf16x8*>(bbase + 3072);
        bqc7 = *reinterpret_cast<const bf16x8*>(bbase + 3584);
    }

    if constexpr (MODE == 0 || MODE == 4) GLA(slab0);

    #pragma unroll 1
    for (int si = 0; si < SLABS_PER_CHUNK; ++si) {
        if constexpr (MODE == 0) {
            CVTWRITE();
            if (si + 1 < SLABS_PER_CHUNK) GLA(slab0 + si + 1);
        }
        if constexpr (MODE == 4) {
            // pin the 16 in-flight loads (forces waitcnt), then reissue
            #pragma unroll
            for (int j = 0; j < 16; ++j) pin4(&sreg[j]);
            if (si + 1 < SLABS_PER_CHUNK) GLA(slab0 + si + 1);
        }
        const int skt = (slab0 + si) * 8;
        if constexpr (MODE == 0 || MODE == 2 || MODE == 3) {
            #pragma unroll
            for (int kts = 0; kts < 8; ++kts) {
                const unsigned short* bk = bbase + (size_t)(skt + kts) * (NCB * 512);
                if constexpr (MODE == 0) {
                    bf16x8 af = *reinterpret_cast<const bf16x8*>(
                        &aLds[w][l15][(kts * 32 + quad * 8) ^ ((l15 & 7) << 3)]);
                    #pragma unroll
                    for (int ct = 0; ct < 8; ++ct) {
                        bf16x8 bq = *reinterpret_cast<const bf16x8*>(bk + ct * 512);
                        acc[ct] = __builtin_amdgcn_mfma_f32_16x16x32_bf16(af, bq, acc[ct], 0, 0, 0);
                    }
                }
                if constexpr (MODE == 2) {
                    #pragma unroll
                    for (int ct = 0; ct < 8; ++ct) {
                        bf16x8 bq = *reinterpret_cast<const bf16x8*>(bk + ct * 512);
                        pin4(&bq);
                    }
                }
                if constexpr (MODE == 3) {
                    acc[0] = __builtin_amdgcn_mfma_f32_16x16x32_bf16(afc, bqc0, acc[0], 0, 0, 0);
                    acc[1] = __builtin_amdgcn_mfma_f32_16x16x32_bf16(afc, bqc1, acc[1], 0, 0, 0);
                    acc[2] = __builtin_amdgcn_mfma_f32_16x16x32_bf16(afc, bqc2, acc[2], 0, 0, 0);
                    acc[3] = __builtin_amdgcn_mfma_f32_16x16x32_bf16(afc, bqc3, acc[3], 0, 0, 0);
                    acc[4] = __builtin_amdgcn_mfma_f32_16x16x32_bf16(afc, bqc4, acc[4], 0, 0, 0);
                    acc[5] = __builtin_amdgcn_mfma_f32_16x16x32_bf16(afc, bqc5, acc[5], 0, 0, 0);
                    acc[6] = __builtin_amdgcn_mfma_f32_16x16x32_bf16(afc, bqc6, acc[6], 0, 0, 0);
                    acc[7] = __builtin_amdgcn_mfma_f32_16x16x32_bf16(afc, bqc7, acc[7], 0, 0, 0);
                }
            }
        }
    }

    float* rp = reps8 + (((size_t)kc * 3 + s) * NROW + rbase) * DDIM;
    #pragma unroll
    for (int ct = 0; ct < 8; ++ct)
        #pragma unroll
        for (int r = 0; r < 4; ++r)
            rp[(size_t)(quad * 4 + r) * DDIM + ct * 16 + l15] = acc[ct][r];
#undef CVTWRITE
#undef GLA
}

// ---------------------------------------------------------------------------
// Kernel 3: reduce 8 partial chunks + row dots + hinge loss. wave-per-row.
// ---------------------------------------------------------------------------
__global__ __launch_bounds__(256) void finalize8(
    const float* __restrict__ reps8, float* __restrict__ out)
{
    __shared__ float ls[4];
    const int wid  = threadIdx.x >> 6;
    const int lane = threadIdx.x & 63;
    const int row  = blockIdx.x * 4 + wid;

    float2 cs = {0.f, 0.f}, rs = {0.f, 0.f}, ns = {0.f, 0.f};
    #pragma unroll
    for (int kc = 0; kc < KSPLIT; ++kc) {
        const float* base = reps8 + ((size_t)kc * 3 * NROW + row) * DDIM + 2 * lane;
        const float2 cv = *reinterpret_cast<const float2*>(base);
        const float2 rv = *reinterpret_cast<const float2*>(base + (size_t)NROW * DDIM);
        const float2 nv = *reinterpret_cast<const float2*>(base + (size_t)2 * NROW * DDIM);
        cs.x += cv.x; cs.y += cv.y;
        rs.x += rv.x; rs.y += rv.y;
        ns.x += nv.x; ns.y += nv.y;
    }

    float fp = cs.x * rs.x + cs.y * rs.y;
    float fn = cs.x * ns.x + cs.y * ns.y;
    #pragma unroll
    for (int off = 32; off > 0; off >>= 1) {
        fp += __shfl_down(fp, off);
        fn += __shfl_down(fn, off);
    }
    if (lane == 0) {
        out[row]        = fp;
        out[NROW + row] = fn;
        float t = fn - fp + 0.5f;
        ls[wid] = t > 0.f ? t : 0.f;
    }
    __syncthreads();
    if (threadIdx.x == 0)
        atomicAdd(out + 2 * NROW, ls[0] + ls[1] + ls[2] + ls[3]);
}

// ---------------------------------------------------------------------------
extern "C" void kernel_launch(void* const* d_in, const int* in_sizes, int n_in,
                              void* d_out, int out_size, void* d_ws, size_t ws_size,
                              hipStream_t stream)
{
    const float* cb  = (const float*)d_in[0];
    const float* rbb = (const float*)d_in[1];
    const float* nb  = (const float*)d_in[2];
    const float* ce  = (const float*)d_in[3];
    const float* re  = (const float*)d_in[4];
    float* out = (float*)d_out;

    unsigned short* embF = (unsigned short*)d_ws;
    const size_t embBytes = (size_t)2 * KTPAD * NCB * 512 * sizeof(unsigned short); // 5.24 MB
    float* reps8 = (float*)((char*)d_ws + embBytes);

    const dim3 grid(NROW / 64, 3, KSPLIT), blk(256);

    build_embF<<<dim3((2 * KTPAD * NCB * 64 + 255) / 256), blk, 0, stream>>>(ce, re, embF);
    hipMemsetAsync(out + 2 * NROW, 0, sizeof(float), stream);

    // ablation probes (results overwritten by the full pass below)
    gemm_abl<4><<<grid, blk, 0, stream>>>(cb, rbb, nb, embF, reps8);  // A glb only
    gemm_abl<2><<<grid, blk, 0, stream>>>(cb, rbb, nb, embF, reps8);  // B loads only
    gemm_abl<3><<<grid, blk, 0, stream>>>(cb, rbb, nb, embF, reps8);  // MFMA only
    // the real computation (writes every reps8 element)
    gemm_abl<0><<<grid, blk, 0, stream>>>(cb, rbb, nb, embF, reps8);
    finalize8<<<dim3(NROW / 4), blk, 0, stream>>>(reps8, out);
}

// Round 16
// 398.957 us; speedup vs baseline: 1.0848x; 1.0848x over previous
//
#include <hip/hip_runtime.h>
#include <cstdint>

#define VDIM 10000
#define NROW 4096
#define DDIM 128
#define KTPAD 320           // kt steps padded (320*32 = 10240)
#define SLABS 40            // 40 slabs x 8 kt x 32 k = full K (10240)
#define NCB 8               // 16-col blocks per kt tile

typedef __attribute__((ext_vector_type(8))) short bf16x8;
typedef __attribute__((ext_vector_type(4))) float f32x4;

__device__ __forceinline__ unsigned short f2bf(float f) {
    union { float f; unsigned u; } v; v.f = f;
    unsigned u = v.u;
    unsigned r = (u + 0x7FFFu + ((u >> 16) & 1u)) >> 16;  // RNE
    return (unsigned short)r;
}

// ---------------------------------------------------------------------------
// Kernel 1: build fragment-major B: embF[e][kt][cb][lane][8] bf16, kt < 320
//   value = emb_e[col = cb*16 + (lane&15)][k = kt*32 + (lane>>4)*8 + j]
// Zero for k+8 > VDIM and all kt >= 313.
// ---------------------------------------------------------------------------
__global__ __launch_bounds__(256) void build_embF(
    const float* __restrict__ ec, const float* __restrict__ er,
    unsigned short* __restrict__ embF)
{
    const int t = blockIdx.x * 256 + threadIdx.x;
    const int perE = KTPAD * NCB * 64;                 // 163840
    if (t >= 2 * perE) return;
    const int e    = t / perE;
    const int rem  = t - e * perE;
    const int kt   = rem >> 9;
    const int rem2 = rem & 511;
    const int cb   = rem2 >> 6;
    const int lane = rem2 & 63;
    const int col  = cb * 16 + (lane & 15);
    const int k0   = kt * 32 + (lane >> 4) * 8;

    unsigned short o[8];
    if (k0 + 8 <= VDIM) {
        const float* src = (e ? er : ec) + (size_t)col * VDIM + k0;
        #pragma unroll
        for (int j = 0; j < 8; ++j) o[j] = f2bf(src[j]);
    } else {
        #pragma unroll
        for (int j = 0; j < 8; ++j) o[j] = 0;
    }
    *reinterpret_cast<bf16x8*>(embF + (size_t)t * 8) =
        *reinterpret_cast<const bf16x8*>(o);
}

// ---------------------------------------------------------------------------
// Kernel 2: three GEMMs [4096,10000]x[10000,128] -> reps[3][4096][128] f32.
// grid = (64 rb x 3 s) = 192 blocks, FULL K per block (the fix: each A row
// is ONE long sequential stream -> DRAM page locality). block = 256 (4 waves);
// wave owns 16 rows x 128 cols (acc[8]).
// A path: per 8-kt slab, 16 fully-coalesced 1KB loads (lane i: 16B at
// row_j + si*1KB + i*16B), cvt_pk -> bf16, XOR-swizzled wave-private LDS.
// No barriers (same-wave DS in-order). B: fragment-major embF, L2-hot.
// Epilogue: PLAIN stores (block owns its rows fully; no atomics).
// ---------------------------------------------------------------------------
__global__ __launch_bounds__(256, 2) void gemm_rep(
    const float* __restrict__ a0, const float* __restrict__ a1,
    const float* __restrict__ a2,
    const unsigned short* __restrict__ embF,
    float* __restrict__ reps)                 // [3][4096][128] f32
{
    __shared__ short aLds[4][16][256];        // 32 KB, wave-private sections

    const int rb = blockIdx.x;                // 64 row-blocks of 64 rows
    const int s  = blockIdx.y;
    const float* A = (s == 0) ? a0 : (s == 1 ? a1 : a2);
    const int e = (s == 0) ? 0 : 1;

    const int tid  = threadIdx.x;
    const int lane = tid & 63;
    const int w    = tid >> 6;
    const int l15  = lane & 15;
    const int quad = lane >> 4;

    const int rbase = rb * 64 + w * 16;       // wave's 16 rows
    const float* arow0 = A + (size_t)rbase * VDIM;

    const unsigned short* bbase =
        embF + (size_t)e * KTPAD * NCB * 512 + (size_t)lane * 8;

    f32x4 acc[8];
    #pragma unroll
    for (int ct = 0; ct < 8; ++ct) acc[ct] = (f32x4){0.f, 0.f, 0.f, 0.f};

    f32x4 sreg[16];                           // staged A slab (16 rows x 16B/lane)

#define GLA(SL) do {                                                   \
        int f_ = (SL) * 256 + lane * 4;                                \
        f_ = f_ > (VDIM - 4) ? (VDIM - 4) : f_;                        \
        _Pragma("unroll")                                              \
        for (int j = 0; j < 16; ++j)                                   \
            sreg[j] = *reinterpret_cast<const f32x4*>(                 \
                arow0 + (size_t)j * VDIM + f_);                        \
    } while (0)

#define CVTWRITE() do {                                                \
        _Pragma("unroll")                                              \
        for (int j = 0; j < 16; ++j) {                                 \
            union { unsigned u[2]; } p_;                               \
            asm("v_cvt_pk_bf16_f32 %0, %1, %2"                         \
                : "=v"(p_.u[0]) : "v"(sreg[j][0]), "v"(sreg[j][1]));   \
            asm("v_cvt_pk_bf16_f32 %0, %1, %2"                         \
                : "=v"(p_.u[1]) : "v"(sreg[j][2]), "v"(sreg[j][3]));   \
            int col_ = (lane * 4) ^ ((j & 7) << 3);                    \
            *reinterpret_cast<uint2*>(&aLds[w][j][col_]) =             \
                *reinterpret_cast<const uint2*>(p_.u);                 \
        }                                                              \
    } while (0)

    // ---- prologue
    GLA(0);

    #pragma unroll 1
    for (int si = 0; si < SLABS; ++si) {
        CVTWRITE();                           // waits A(si) progressively
        if (si + 1 < SLABS) GLA(si + 1);      // next 1KB of the SAME rows
        const int skt = si * 8;
        #pragma unroll
        for (int kts = 0; kts < 8; ++kts) {
            const unsigned short* bk = bbase + (size_t)(skt + kts) * (NCB * 512);
            bf16x8 af = *reinterpret_cast<const bf16x8*>(
                &aLds[w][l15][(kts * 32 + quad * 8) ^ ((l15 & 7) << 3)]);
            #pragma unroll
            for (int ct = 0; ct < 8; ++ct) {
                bf16x8 bq = *reinterpret_cast<const bf16x8*>(bk + ct * 512);
                acc[ct] = __builtin_amdgcn_mfma_f32_16x16x32_bf16(af, bq, acc[ct], 0, 0, 0);
            }
        }
    }

    // epilogue: C/D layout col = lane&15, row = quad*4 + reg — plain stores
    float* rp = reps + ((size_t)s * NROW + rbase) * DDIM;
    #pragma unroll
    for (int ct = 0; ct < 8; ++ct)
        #pragma unroll
        for (int r = 0; r < 4; ++r)
            rp[(size_t)(quad * 4 + r) * DDIM + ct * 16 + l15] = acc[ct][r];
#undef CVTWRITE
#undef GLA
}

// ---------------------------------------------------------------------------
// Kernel 3: f_pos/f_neg row dots + hinge loss. wave-per-row, block = 4 waves
// ---------------------------------------------------------------------------
__global__ __launch_bounds__(256) void finalize(
    const float* __restrict__ reps, float* __restrict__ out)
{
    __shared__ float ls[4];
    const int wid  = threadIdx.x >> 6;
    const int lane = threadIdx.x & 63;
    const int row  = blockIdx.x * 4 + wid;

    const float* c = reps + (size_t)row * DDIM + 2 * lane;
    const float2 cv = *reinterpret_cast<const float2*>(c);
    const float2 rv = *reinterpret_cast<const float2*>(c + (size_t)NROW * DDIM);
    const float2 nv = *reinterpret_cast<const float2*>(c + (size_t)2 * NROW * DDIM);

    float fp = cv.x * rv.x + cv.y * rv.y;
    float fn = cv.x * nv.x + cv.y * nv.y;
    #pragma unroll
    for (int off = 32; off > 0; off >>= 1) {
        fp += __shfl_down(fp, off);
        fn += __shfl_down(fn, off);
    }
    if (lane == 0) {
        out[row]        = fp;
        out[NROW + row] = fn;
        float t = fn - fp + 0.5f;
        ls[wid] = t > 0.f ? t : 0.f;
    }
    __syncthreads();
    if (threadIdx.x == 0)
        atomicAdd(out + 2 * NROW, ls[0] + ls[1] + ls[2] + ls[3]);
}

// ---------------------------------------------------------------------------
extern "C" void kernel_launch(void* const* d_in, const int* in_sizes, int n_in,
                              void* d_out, int out_size, void* d_ws, size_t ws_size,
                              hipStream_t stream)
{
    const float* cb  = (const float*)d_in[0];
    const float* rbb = (const float*)d_in[1];
    const float* nb  = (const float*)d_in[2];
    const float* ce  = (const float*)d_in[3];
    const float* re  = (const float*)d_in[4];
    float* out = (float*)d_out;

    unsigned short* embF = (unsigned short*)d_ws;
    const size_t embBytes = (size_t)2 * KTPAD * NCB * 512 * sizeof(unsigned short); // 5.24 MB
    float* reps = (float*)((char*)d_ws + embBytes);                                 // 6.29 MB

    build_embF<<<dim3((2 * KTPAD * NCB * 64 + 255) / 256), dim3(256), 0, stream>>>(ce, re, embF);
    hipMemsetAsync(out + 2 * NROW, 0, sizeof(float), stream);
    gemm_rep<<<dim3(NROW / 64, 3), dim3(256), 0, stream>>>(cb, rbb, nb, embF, reps);
    finalize<<<dim3(NROW / 4), dim3(256), 0, stream>>>(reps, out);
}

// Round 17
// 203.489 us; speedup vs baseline: 2.1268x; 1.9606x over previous
//
#include <hip/hip_runtime.h>
#include <cstdint>

#define VDIM 10000
#define NROW 4096
#define DDIM 128
#define KTPAD 320           // K=32 steps padded (320*32 = 10240)
#define KSPLIT 8
#define NSTEP 20            // BK=64 steps per chunk: 20*64 = 1280 floats
#define NCB 8               // 16-col blocks per kt tile

typedef __attribute__((ext_vector_type(8))) short bf16x8;
typedef __attribute__((ext_vector_type(4))) float f32x4;

__device__ __forceinline__ unsigned short f2bf(float f) {
    union { float f; unsigned u; } v; v.f = f;
    unsigned u = v.u;
    unsigned r = (u + 0x7FFFu + ((u >> 16) & 1u)) >> 16;  // RNE
    return (unsigned short)r;
}

// ---------------------------------------------------------------------------
// Kernel 1: build fragment-major B: embF[e][kt][cb][lane][8] bf16, kt < 320
// ---------------------------------------------------------------------------
__global__ __launch_bounds__(256) void build_embF(
    const float* __restrict__ ec, const float* __restrict__ er,
    unsigned short* __restrict__ embF)
{
    const int t = blockIdx.x * 256 + threadIdx.x;
    const int perE = KTPAD * NCB * 64;                 // 163840
    if (t >= 2 * perE) return;
    const int e    = t / perE;
    const int rem  = t - e * perE;
    const int kt   = rem >> 9;
    const int rem2 = rem & 511;
    const int cb   = rem2 >> 6;
    const int lane = rem2 & 63;
    const int col  = cb * 16 + (lane & 15);
    const int k0   = kt * 32 + (lane >> 4) * 8;

    unsigned short o[8];
    if (k0 + 8 <= VDIM) {
        const float* src = (e ? er : ec) + (size_t)col * VDIM + k0;
        #pragma unroll
        for (int j = 0; j < 8; ++j) o[j] = f2bf(src[j]);
    } else {
        #pragma unroll
        for (int j = 0; j < 8; ++j) o[j] = 0;
    }
    *reinterpret_cast<bf16x8*>(embF + (size_t)t * 8) =
        *reinterpret_cast<const bf16x8*>(o);
}

// ---------------------------------------------------------------------------
// Kernel 2: GEMM with ASYNC A-staging (global_load_lds) — m97/T3 recipe.
// grid = 1536 blocks (64 rb x 3 s x 8 kc, XCD-swizzled); block 256 (4 waves).
// Tile: 64 rows x 128 cols, BK = 64 f32. A-tile f32 [64][64] = 16KB,
// double-buffered (32KB LDS -> 5 blocks/CU). Stage: 4 global_load_lds
// dwordx4 per thread, source pre-swizzled (shift-4 XOR) so swizzled ds_read
// is bank-friendly. One __syncthreads per step; 5 blocks/CU interleave the
// drain (m114). B: fragment-major embF; same-XCD blocks share one kc slice.
// Epilogue: plain stores to per-chunk partials reps8 (no atomics).
// ---------------------------------------------------------------------------
__global__ __launch_bounds__(256, 4) void gemm_rep(
    const float* __restrict__ a0, const float* __restrict__ a1,
    const float* __restrict__ a2,
    const unsigned short* __restrict__ embF,
    float* __restrict__ reps8)                // [8][3][4096][128] f32
{
    __shared__ float aLds[2][4096];           // 2 x 16KB

    // bijective XCD swizzle (1536 % 8 == 0): same-XCD blocks share kc
    const int lid = blockIdx.x;
    const int kc  = lid & 7;
    const int rem = lid >> 3;                 // [0,192)
    const int rb  = rem & 63;
    const int s   = rem >> 6;

    const float* A = (s == 0) ? a0 : (s == 1 ? a1 : a2);
    const int e = (s == 0) ? 0 : 1;

    const int tid  = threadIdx.x;
    const int lane = tid & 63;
    const int w    = tid >> 6;
    const int l15  = lane & 15;
    const int quad = lane >> 4;

    const int rbase = rb * 64;
    const unsigned short* bbase =
        embF + (size_t)e * KTPAD * NCB * 512 + (size_t)lane * 8;

    // staging geometry (per thread, 4 rounds): row = r*16 + tid/16,
    // 16B cell (tid&15), source col pre-swizzled by ((row&7)<<4) bytes
    const int srow_base = tid >> 4;           // + r*16
    const int scell     = (tid & 15) * 16;    // byte col within 256B row

    f32x4 acc[8];
    #pragma unroll
    for (int ct = 0; ct < 8; ++ct) acc[ct] = (f32x4){0.f, 0.f, 0.f, 0.f};

#define STAGE(BUF, STEP) do {                                              \
        const int k0_ = kc * (NSTEP * 64) + (STEP) * 64;                   \
        _Pragma("unroll")                                                  \
        for (int r_ = 0; r_ < 4; ++r_) {                                   \
            const int row_ = r_ * 16 + srow_base;                          \
            int fo_ = k0_ + ((scell ^ ((row_ & 7) << 4)) >> 2);            \
            fo_ = fo_ > (VDIM - 4) ? (VDIM - 4) : fo_;                     \
            __builtin_amdgcn_global_load_lds(                              \
                (const __attribute__((address_space(1))) unsigned int*)    \
                    (A + (size_t)(rbase + row_) * VDIM + fo_),             \
                (__attribute__((address_space(3))) unsigned int*)          \
                    &aLds[BUF][r_ * 1024 + tid * 4],                       \
                16, 0, 0);                                                 \
        }                                                                  \
    } while (0)

#define COMPUTE(BUF, STEP) do {                                            \
        _Pragma("unroll")                                                  \
        for (int h_ = 0; h_ < 2; ++h_) {                                   \
            const int kt_ = kc * (NSTEP * 2) + (STEP) * 2 + h_;            \
            const unsigned short* bk_ = bbase + (size_t)kt_ * (NCB * 512); \
            const int row_ = w * 16 + l15;                                 \
            const int c0_  = h_ * 128 + quad * 32;                         \
            const int sw_  = (row_ & 7) << 4;                              \
            const f32x4 fa_ = *reinterpret_cast<const f32x4*>(             \
                &aLds[BUF][(row_ * 256 + ((c0_) ^ sw_)) >> 2]);            \
            const f32x4 fb_ = *reinterpret_cast<const f32x4*>(             \
                &aLds[BUF][(row_ * 256 + ((c0_ + 16) ^ sw_)) >> 2]);       \
            union { unsigned u[4]; bf16x8 v; } af_;                        \
            asm("v_cvt_pk_bf16_f32 %0, %1, %2"                             \
                : "=v"(af_.u[0]) : "v"(fa_[0]), "v"(fa_[1]));              \
            asm("v_cvt_pk_bf16_f32 %0, %1, %2"                             \
                : "=v"(af_.u[1]) : "v"(fa_[2]), "v"(fa_[3]));              \
            asm("v_cvt_pk_bf16_f32 %0, %1, %2"                             \
                : "=v"(af_.u[2]) : "v"(fb_[0]), "v"(fb_[1]));              \
            asm("v_cvt_pk_bf16_f32 %0, %1, %2"                             \
                : "=v"(af_.u[3]) : "v"(fb_[2]), "v"(fb_[3]));              \
            _Pragma("unroll")                                              \
            for (int ct_ = 0; ct_ < 8; ++ct_) {                            \
                bf16x8 bq_ = *reinterpret_cast<const bf16x8*>(bk_ + ct_ * 512); \
                acc[ct_] = __builtin_amdgcn_mfma_f32_16x16x32_bf16(        \
                    af_.v, bq_, acc[ct_], 0, 0, 0);                        \
            }                                                              \
        }                                                                  \
    } while (0)

    // prologue: stage step 0 into buf 0, publish
    STAGE(0, 0);
    __syncthreads();                          // vmcnt drained by barrier semantics

    int cur = 0;
    #pragma unroll 1
    for (int t = 0; t < NSTEP; ++t) {
        if (t + 1 < NSTEP) STAGE(cur ^ 1, t + 1);   // async, in flight over compute
        COMPUTE(cur, t);
        __syncthreads();                            // drains stage(t+1), publishes
        cur ^= 1;
    }

    // epilogue: C/D layout col = lane&15, row = quad*4 + reg — plain stores
    float* rp = reps8 + (((size_t)kc * 3 + s) * NROW + rbase + w * 16) * DDIM;
    #pragma unroll
    for (int ct = 0; ct < 8; ++ct)
        #pragma unroll
        for (int r = 0; r < 4; ++r)
            rp[(size_t)(quad * 4 + r) * DDIM + ct * 16 + l15] = acc[ct][r];
#undef COMPUTE
#undef STAGE
}

// ---------------------------------------------------------------------------
// Kernel 3: reduce 8 partial chunks + row dots + hinge loss. wave-per-row.
// ---------------------------------------------------------------------------
__global__ __launch_bounds__(256) void finalize8(
    const float* __restrict__ reps8, float* __restrict__ out)
{
    __shared__ float ls[4];
    const int wid  = threadIdx.x >> 6;
    const int lane = threadIdx.x & 63;
    const int row  = blockIdx.x * 4 + wid;

    float2 cs = {0.f, 0.f}, rs = {0.f, 0.f}, ns = {0.f, 0.f};
    #pragma unroll
    for (int kc = 0; kc < KSPLIT; ++kc) {
        const float* base = reps8 + ((size_t)kc * 3 * NROW + row) * DDIM + 2 * lane;
        const float2 cv = *reinterpret_cast<const float2*>(base);
        const float2 rv = *reinterpret_cast<const float2*>(base + (size_t)NROW * DDIM);
        const float2 nv = *reinterpret_cast<const float2*>(base + (size_t)2 * NROW * DDIM);
        cs.x += cv.x; cs.y += cv.y;
        rs.x += rv.x; rs.y += rv.y;
        ns.x += nv.x; ns.y += nv.y;
    }

    float fp = cs.x * rs.x + cs.y * rs.y;
    float fn = cs.x * ns.x + cs.y * ns.y;
    #pragma unroll
    for (int off = 32; off > 0; off >>= 1) {
        fp += __shfl_down(fp, off);
        fn += __shfl_down(fn, off);
    }
    if (lane == 0) {
        out[row]        = fp;
        out[NROW + row] = fn;
        float t = fn - fp + 0.5f;
        ls[wid] = t > 0.f ? t : 0.f;
    }
    __syncthreads();
    if (threadIdx.x == 0)
        atomicAdd(out + 2 * NROW, ls[0] + ls[1] + ls[2] + ls[3]);
}

// ---------------------------------------------------------------------------
extern "C" void kernel_launch(void* const* d_in, const int* in_sizes, int n_in,
                              void* d_out, int out_size, void* d_ws, size_t ws_size,
                              hipStream_t stream)
{
    const float* cb  = (const float*)d_in[0];
    const float* rbb = (const float*)d_in[1];
    const float* nb  = (const float*)d_in[2];
    const float* ce  = (const float*)d_in[3];
    const float* re  = (const float*)d_in[4];
    float* out = (float*)d_out;

    unsigned short* embF = (unsigned short*)d_ws;
    const size_t embBytes = (size_t)2 * KTPAD * NCB * 512 * sizeof(unsigned short); // 5.24 MB
    float* reps8 = (float*)((char*)d_ws + embBytes);                                // 50.3 MB

    build_embF<<<dim3((2 * KTPAD * NCB * 64 + 255) / 256), dim3(256), 0, stream>>>(ce, re, embF);
    hipMemsetAsync(out + 2 * NROW, 0, sizeof(float), stream);
    gemm_rep<<<dim3(64 * 3 * KSPLIT), dim3(256), 0, stream>>>(cb, rbb, nb, embF, reps8);
    finalize8<<<dim3(NROW / 4), dim3(256), 0, stream>>>(reps8, out);
}

// Round 18
// 194.165 us; speedup vs baseline: 2.2290x; 1.0480x over previous
//
#include <hip/hip_runtime.h>
#include <cstdint>

#define VDIM 10000
#define NROW 4096
#define DDIM 128
#define KTPAD 320           // K=32 steps padded (320*32 = 10240)
#define KSPLIT 8
#define SLABS_PER_CHUNK 10  // 10 slabs x 128 floats = 1280 floats per chunk
#define NCB 8               // 16-col blocks per kt tile

typedef __attribute__((ext_vector_type(8))) short bf16x8;
typedef __attribute__((ext_vector_type(4))) float f32x4;
typedef __attribute__((ext_vector_type(2))) float f32x2;

__device__ __forceinline__ unsigned short f2bf(float f) {
    union { float f; unsigned u; } v; v.f = f;
    unsigned u = v.u;
    unsigned r = (u + 0x7FFFu + ((u >> 16) & 1u)) >> 16;  // RNE
    return (unsigned short)r;
}

// ---------------------------------------------------------------------------
// Kernel 1: build fragment-major B: embF[e][kt][cb][lane][8] bf16, kt < 320
// ---------------------------------------------------------------------------
__global__ __launch_bounds__(256) void build_embF(
    const float* __restrict__ ec, const float* __restrict__ er,
    unsigned short* __restrict__ embF)
{
    const int t = blockIdx.x * 256 + threadIdx.x;
    const int perE = KTPAD * NCB * 64;                 // 163840
    if (t >= 2 * perE) return;
    const int e    = t / perE;
    const int rem  = t - e * perE;
    const int kt   = rem >> 9;
    const int rem2 = rem & 511;
    const int cb   = rem2 >> 6;
    const int lane = rem2 & 63;
    const int col  = cb * 16 + (lane & 15);
    const int k0   = kt * 32 + (lane >> 4) * 8;

    unsigned short o[8];
    if (k0 + 8 <= VDIM) {
        const float* src = (e ? er : ec) + (size_t)col * VDIM + k0;
        #pragma unroll
        for (int j = 0; j < 8; ++j) o[j] = f2bf(src[j]);
    } else {
        #pragma unroll
        for (int j = 0; j < 8; ++j) o[j] = 0;
    }
    *reinterpret_cast<bf16x8*>(embF + (size_t)t * 8) =
        *reinterpret_cast<const bf16x8*>(o);
}

// ---------------------------------------------------------------------------
// Kernel 2: three GEMMs -> per-chunk partials reps8[kc][s][4096][128] f32.
// grid = 1536 blocks (flattened, kc = bid&7 -> same-XCD blocks share the
// embF kc slice: T1). block = 256 (4 waves); wave owns 16 rows x 128 cols.
// A: per 512B slab, 16 coalesced f32x2 loads (8B/lane), cvt_pk -> bf16,
// XOR-swizzled wave-private LDS [16][128] shorts (4KB/wave, 16KB/block).
// No barriers (same-wave DS in-order, single buffer, WAR by DS queue order).
// B: fragment-major embF (L2-hot per XCD). Epilogue: plain stores.
// ---------------------------------------------------------------------------
__global__ __launch_bounds__(256, 4) void gemm_rep(
    const float* __restrict__ a0, const float* __restrict__ a1,
    const float* __restrict__ a2,
    const unsigned short* __restrict__ embF,
    float* __restrict__ reps8)                // [8][3][4096][128] f32
{
    __shared__ short aLds[4][16][128];        // 16 KB, wave-private sections

    const int lid = blockIdx.x;               // 0..1535
    const int kc  = lid & 7;                  // same-XCD blocks share kc
    const int rem = lid >> 3;                 // 0..191
    const int rb  = rem & 63;
    const int s   = rem >> 6;

    const float* A = (s == 0) ? a0 : (s == 1 ? a1 : a2);
    const int e = (s == 0) ? 0 : 1;

    const int tid  = threadIdx.x;
    const int lane = tid & 63;
    const int w    = tid >> 6;
    const int l15  = lane & 15;
    const int quad = lane >> 4;

    const int rbase = rb * 64 + w * 16;       // wave's 16 rows
    const float* arow0 = A + (size_t)rbase * VDIM;
    const int kbase  = kc * (SLABS_PER_CHUNK * 128);   // float offset
    const int ktbase = kc * (SLABS_PER_CHUNK * 4);     // K-step offset

    const unsigned short* bbase =
        embF + (size_t)e * KTPAD * NCB * 512 + (size_t)lane * 8;

    f32x4 acc[8];
    #pragma unroll
    for (int ct = 0; ct < 8; ++ct) acc[ct] = (f32x4){0.f, 0.f, 0.f, 0.f};

    f32x2 sreg[16];                           // staged A slab (16 rows x 8B/lane)

#define GLA(SL) do {                                                   \
        int f_ = kbase + (SL) * 128 + lane * 2;                        \
        f_ = f_ > (VDIM - 2) ? (VDIM - 2) : f_;                        \
        _Pragma("unroll")                                              \
        for (int j = 0; j < 16; ++j)                                   \
            sreg[j] = *reinterpret_cast<const f32x2*>(                 \
                arow0 + (size_t)j * VDIM + f_);                        \
    } while (0)

#define CVTWRITE() do {                                                \
        _Pragma("unroll")                                              \
        for (int j = 0; j < 16; ++j) {                                 \
            unsigned p_;                                               \
            asm("v_cvt_pk_bf16_f32 %0, %1, %2"                         \
                : "=v"(p_) : "v"(sreg[j][0]), "v"(sreg[j][1]));        \
            const int col_ = (lane * 2) ^ ((j & 7) << 3);              \
            *reinterpret_cast<unsigned*>(&aLds[w][j][col_]) = p_;      \
        }                                                              \
    } while (0)

    // ---- prologue
    GLA(0);

    #pragma unroll 1
    for (int si = 0; si < SLABS_PER_CHUNK; ++si) {
        CVTWRITE();                           // consumes A(si) as loads land
        if (si + 1 < SLABS_PER_CHUNK) GLA(si + 1);  // next 512B of same rows
        #pragma unroll
        for (int kts = 0; kts < 4; ++kts) {
            const int kt = ktbase + si * 4 + kts;
            const unsigned short* bk = bbase + (size_t)kt * (NCB * 512);
            bf16x8 af = *reinterpret_cast<const bf16x8*>(
                &aLds[w][l15][(kts * 32 + quad * 8) ^ ((l15 & 7) << 3)]);
            #pragma unroll
            for (int ct = 0; ct < 8; ++ct) {
                bf16x8 bq = *reinterpret_cast<const bf16x8*>(bk + ct * 512);
                acc[ct] = __builtin_amdgcn_mfma_f32_16x16x32_bf16(af, bq, acc[ct], 0, 0, 0);
            }
        }
    }

    // epilogue: C/D layout col = lane&15, row = quad*4 + reg — plain stores
    float* rp = reps8 + (((size_t)kc * 3 + s) * NROW + rbase) * DDIM;
    #pragma unroll
    for (int ct = 0; ct < 8; ++ct)
        #pragma unroll
        for (int r = 0; r < 4; ++r)
            rp[(size_t)(quad * 4 + r) * DDIM + ct * 16 + l15] = acc[ct][r];
#undef CVTWRITE
#undef GLA
}

// ---------------------------------------------------------------------------
// Kernel 3: reduce 8 partial chunks + row dots + hinge loss. wave-per-row.
// ---------------------------------------------------------------------------
__global__ __launch_bounds__(256) void finalize8(
    const float* __restrict__ reps8, float* __restrict__ out)
{
    __shared__ float ls[4];
    const int wid  = threadIdx.x >> 6;
    const int lane = threadIdx.x & 63;
    const int row  = blockIdx.x * 4 + wid;

    float2 cs = {0.f, 0.f}, rs = {0.f, 0.f}, ns = {0.f, 0.f};
    #pragma unroll
    for (int kc = 0; kc < KSPLIT; ++kc) {
        const float* base = reps8 + ((size_t)kc * 3 * NROW + row) * DDIM + 2 * lane;
        const float2 cv = *reinterpret_cast<const float2*>(base);
        const float2 rv = *reinterpret_cast<const float2*>(base + (size_t)NROW * DDIM);
        const float2 nv = *reinterpret_cast<const float2*>(base + (size_t)2 * NROW * DDIM);
        cs.x += cv.x; cs.y += cv.y;
        rs.x += rv.x; rs.y += rv.y;
        ns.x += nv.x; ns.y += nv.y;
    }

    float fp = cs.x * rs.x + cs.y * rs.y;
    float fn = cs.x * ns.x + cs.y * ns.y;
    #pragma unroll
    for (int off = 32; off > 0; off >>= 1) {
        fp += __shfl_down(fp, off);
        fn += __shfl_down(fn, off);
    }
    if (lane == 0) {
        out[row]        = fp;
        out[NROW + row] = fn;
        float t = fn - fp + 0.5f;
        ls[wid] = t > 0.f ? t : 0.f;
    }
    __syncthreads();
    if (threadIdx.x == 0)
        atomicAdd(out + 2 * NROW, ls[0] + ls[1] + ls[2] + ls[3]);
}

// ---------------------------------------------------------------------------
extern "C" void kernel_launch(void* const* d_in, const int* in_sizes, int n_in,
                              void* d_out, int out_size, void* d_ws, size_t ws_size,
                              hipStream_t stream)
{
    const float* cb  = (const float*)d_in[0];
    const float* rbb = (const float*)d_in[1];
    const float* nb  = (const float*)d_in[2];
    const float* ce  = (const float*)d_in[3];
    const float* re  = (const float*)d_in[4];
    float* out = (float*)d_out;

    unsigned short* embF = (unsigned short*)d_ws;
    const size_t embBytes = (size_t)2 * KTPAD * NCB * 512 * sizeof(unsigned short); // 5.24 MB
    float* reps8 = (float*)((char*)d_ws + embBytes);                                // 50.3 MB

    build_embF<<<dim3((2 * KTPAD * NCB * 64 + 255) / 256), dim3(256), 0, stream>>>(ce, re, embF);
    hipMemsetAsync(out + 2 * NROW, 0, sizeof(float), stream);
    gemm_rep<<<dim3(64 * 3 * KSPLIT), dim3(256), 0, stream>>>(cb, rbb, nb, embF, reps8);
    finalize8<<<dim3(NROW / 4), dim3(256), 0, stream>>>(reps8, out);
}

// Round 19
// 189.419 us; speedup vs baseline: 2.2848x; 1.0251x over previous
//
#include <hip/hip_runtime.h>
#include <cstdint>

#define VDIM 10000
#define NROW 4096
#define DDIM 128
#define KTPAD 320           // K=32 steps padded (320*32 = 10240)
#define KSPLIT 8
#define SLABS_PER_CHUNK 10  // 10 slabs x 128 floats = 1280 floats per chunk
#define NCB 8               // 16-col blocks per kt tile

typedef __attribute__((ext_vector_type(8))) short bf16x8;
typedef __attribute__((ext_vector_type(4))) float f32x4;
typedef __attribute__((ext_vector_type(2))) float f32x2;

__device__ __forceinline__ unsigned short f2bf(float f) {
    union { float f; unsigned u; } v; v.f = f;
    unsigned u = v.u;
    unsigned r = (u + 0x7FFFu + ((u >> 16) & 1u)) >> 16;  // RNE
    return (unsigned short)r;
}

// ---------------------------------------------------------------------------
// Kernel 1: build fragment-major B: embF[e][kt][cb][lane][8] bf16, kt < 320
// ---------------------------------------------------------------------------
__global__ __launch_bounds__(256) void build_embF(
    const float* __restrict__ ec, const float* __restrict__ er,
    unsigned short* __restrict__ embF)
{
    const int t = blockIdx.x * 256 + threadIdx.x;
    const int perE = KTPAD * NCB * 64;                 // 163840
    if (t >= 2 * perE) return;
    const int e    = t / perE;
    const int rem  = t - e * perE;
    const int kt   = rem >> 9;
    const int rem2 = rem & 511;
    const int cb   = rem2 >> 6;
    const int lane = rem2 & 63;
    const int col  = cb * 16 + (lane & 15);
    const int k0   = kt * 32 + (lane >> 4) * 8;

    unsigned short o[8];
    if (k0 + 8 <= VDIM) {
        const float* src = (e ? er : ec) + (size_t)col * VDIM + k0;
        #pragma unroll
        for (int j = 0; j < 8; ++j) o[j] = f2bf(src[j]);
    } else {
        #pragma unroll
        for (int j = 0; j < 8; ++j) o[j] = 0;
    }
    *reinterpret_cast<bf16x8*>(embF + (size_t)t * 8) =
        *reinterpret_cast<const bf16x8*>(o);
}

// ---------------------------------------------------------------------------
// Kernel 2: three GEMMs -> per-chunk partials reps8[kc][s][4096][128] f32.
// grid = 1536 (kc = bid&7: same-XCD blocks share embF kc slice).
// block = 256 = 4 waves as 2 row-waves x 2 col-waves; wave = 32 rows x 64 cols.
//   -> B L1-traffic per block-kt halves vs 16x128 tiles (16KB vs 32KB);
//   -> per-wave A queue doubles (32 f32x2 loads in flight at each drain).
// A: per 512B slab, 32 coalesced f32x2 loads, cvt_pk, XOR-swizzled
// wave-private LDS [32][128] shorts (8KB/wave). No barriers.
// B: fragment-major embF (L2-hot). Epilogue: plain stores (no atomics).
// ---------------------------------------------------------------------------
__global__ __launch_bounds__(256, 3) void gemm_rep(
    const float* __restrict__ a0, const float* __restrict__ a1,
    const float* __restrict__ a2,
    const unsigned short* __restrict__ embF,
    float* __restrict__ reps8)                // [8][3][4096][128] f32
{
    __shared__ short aLds[4][32][128];        // 32 KB, wave-private sections

    const int lid = blockIdx.x;               // 0..1535
    const int kc  = lid & 7;
    const int rem = lid >> 3;                 // 0..191
    const int rb  = rem & 63;
    const int s   = rem >> 6;

    const float* A = (s == 0) ? a0 : (s == 1 ? a1 : a2);
    const int e = (s == 0) ? 0 : 1;

    const int tid  = threadIdx.x;
    const int lane = tid & 63;
    const int w    = tid >> 6;
    const int wr   = w >> 1;                  // row half
    const int wc   = w & 1;                   // col half
    const int l15  = lane & 15;
    const int quad = lane >> 4;

    const int rbase = rb * 64 + wr * 32;      // wave's 32 rows
    const float* arow0 = A + (size_t)rbase * VDIM;
    const int kbase  = kc * (SLABS_PER_CHUNK * 128);   // float offset
    const int ktbase = kc * (SLABS_PER_CHUNK * 4);     // K-step offset

    // B fragment base for this wave's col half: frags wc*4 + ct
    const unsigned short* bbase =
        embF + ((size_t)e * KTPAD * NCB + wc * 4) * 512 + (size_t)lane * 8;

    f32x4 acc[2][4];
    #pragma unroll
    for (int rf = 0; rf < 2; ++rf)
        #pragma unroll
        for (int ct = 0; ct < 4; ++ct) acc[rf][ct] = (f32x4){0.f, 0.f, 0.f, 0.f};

    f32x2 sreg[32];                           // staged A slab (32 rows x 8B/lane)

#define GLA(SL) do {                                                   \
        int f_ = kbase + (SL) * 128 + lane * 2;                        \
        f_ = f_ > (VDIM - 2) ? (VDIM - 2) : f_;                        \
        _Pragma("unroll")                                              \
        for (int j = 0; j < 32; ++j)                                   \
            sreg[j] = *reinterpret_cast<const f32x2*>(                 \
                arow0 + (size_t)j * VDIM + f_);                        \
    } while (0)

#define CVTWRITE() do {                                                \
        _Pragma("unroll")                                              \
        for (int j = 0; j < 32; ++j) {                                 \
            unsigned p_;                                               \
            asm("v_cvt_pk_bf16_f32 %0, %1, %2"                         \
                : "=v"(p_) : "v"(sreg[j][0]), "v"(sreg[j][1]));        \
            const int col_ = (lane * 2) ^ ((j & 7) << 3);              \
            *reinterpret_cast<unsigned*>(&aLds[w][j][col_]) = p_;      \
        }                                                              \
    } while (0)

    // ---- prologue
    GLA(0);

    #pragma unroll 1
    for (int si = 0; si < SLABS_PER_CHUNK; ++si) {
        CVTWRITE();                           // consumes A(si) as loads land
        if (si + 1 < SLABS_PER_CHUNK) GLA(si + 1);
        #pragma unroll
        for (int kts = 0; kts < 4; ++kts) {
            const int kt = ktbase + si * 4 + kts;
            const unsigned short* bk = bbase + (size_t)kt * (NCB * 512);
            bf16x8 af0 = *reinterpret_cast<const bf16x8*>(
                &aLds[w][l15][(kts * 32 + quad * 8) ^ ((l15 & 7) << 3)]);
            bf16x8 af1 = *reinterpret_cast<const bf16x8*>(
                &aLds[w][16 + l15][(kts * 32 + quad * 8) ^ ((l15 & 7) << 3)]);
            #pragma unroll
            for (int ct = 0; ct < 4; ++ct) {
                bf16x8 bq = *reinterpret_cast<const bf16x8*>(bk + ct * 512);
                acc[0][ct] = __builtin_amdgcn_mfma_f32_16x16x32_bf16(af0, bq, acc[0][ct], 0, 0, 0);
                acc[1][ct] = __builtin_amdgcn_mfma_f32_16x16x32_bf16(af1, bq, acc[1][ct], 0, 0, 0);
            }
        }
    }

    // epilogue: C/D layout col = lane&15, row = quad*4 + reg — plain stores
    float* rp = reps8 + (((size_t)kc * 3 + s) * NROW + rbase) * DDIM + wc * 64;
    #pragma unroll
    for (int rf = 0; rf < 2; ++rf)
        #pragma unroll
        for (int ct = 0; ct < 4; ++ct)
            #pragma unroll
            for (int r = 0; r < 4; ++r)
                rp[(size_t)(rf * 16 + quad * 4 + r) * DDIM + ct * 16 + l15]
                    = acc[rf][ct][r];
#undef CVTWRITE
#undef GLA
}

// ---------------------------------------------------------------------------
// Kernel 3: reduce 8 partial chunks + row dots + hinge loss. wave-per-row.
// ---------------------------------------------------------------------------
__global__ __launch_bounds__(256) void finalize8(
    const float* __restrict__ reps8, float* __restrict__ out)
{
    __shared__ float ls[4];
    const int wid  = threadIdx.x >> 6;
    const int lane = threadIdx.x & 63;
    const int row  = blockIdx.x * 4 + wid;

    float2 cs = {0.f, 0.f}, rs = {0.f, 0.f}, ns = {0.f, 0.f};
    #pragma unroll
    for (int kc = 0; kc < KSPLIT; ++kc) {
        const float* base = reps8 + ((size_t)kc * 3 * NROW + row) * DDIM + 2 * lane;
        const float2 cv = *reinterpret_cast<const float2*>(base);
        const float2 rv = *reinterpret_cast<const float2*>(base + (size_t)NROW * DDIM);
        const float2 nv = *reinterpret_cast<const float2*>(base + (size_t)2 * NROW * DDIM);
        cs.x += cv.x; cs.y += cv.y;
        rs.x += rv.x; rs.y += rv.y;
        ns.x += nv.x; ns.y += nv.y;
    }

    float fp = cs.x * rs.x + cs.y * rs.y;
    float fn = cs.x * ns.x + cs.y * ns.y;
    #pragma unroll
    for (int off = 32; off > 0; off >>= 1) {
        fp += __shfl_down(fp, off);
        fn += __shfl_down(fn, off);
    }
    if (lane == 0) {
        out[row]        = fp;
        out[NROW + row] = fn;
        float t = fn - fp + 0.5f;
        ls[wid] = t > 0.f ? t : 0.f;
    }
    __syncthreads();
    if (threadIdx.x == 0)
        atomicAdd(out + 2 * NROW, ls[0] + ls[1] + ls[2] + ls[3]);
}

// ---------------------------------------------------------------------------
extern "C" void kernel_launch(void* const* d_in, const int* in_sizes, int n_in,
                              void* d_out, int out_size, void* d_ws, size_t ws_size,
                              hipStream_t stream)
{
    const float* cb  = (const float*)d_in[0];
    const float* rbb = (const float*)d_in[1];
    const float* nb  = (const float*)d_in[2];
    const float* ce  = (const float*)d_in[3];
    const float* re  = (const float*)d_in[4];
    float* out = (float*)d_out;

    unsigned short* embF = (unsigned short*)d_ws;
    const size_t embBytes = (size_t)2 * KTPAD * NCB * 512 * sizeof(unsigned short); // 5.24 MB
    float* reps8 = (float*)((char*)d_ws + embBytes);                                // 50.3 MB

    build_embF<<<dim3((2 * KTPAD * NCB * 64 + 255) / 256), dim3(256), 0, stream>>>(ce, re, embF);
    hipMemsetAsync(out + 2 * NROW, 0, sizeof(float), stream);
    gemm_rep<<<dim3(64 * 3 * KSPLIT), dim3(256), 0, stream>>>(cb, rbb, nb, embF, reps8);
    finalize8<<<dim3(NROW / 4), dim3(256), 0, stream>>>(reps8, out);
}

// Round 20
// 176.725 us; speedup vs baseline: 2.4489x; 1.0718x over previous
//
#include <hip/hip_runtime.h>
#include <cstdint>

#define VDIM 10000
#define NROW 4096
#define DDIM 128
#define KTPAD 320           // kt steps padded (320*32 = 10240)
#define KSPLIT 8
#define SLABS_PER_CHUNK 5   // 5 slabs * 8 kt * 32 k = 1280 k per chunk
#define NCB 8               // 16-col blocks per kt tile

typedef __attribute__((ext_vector_type(8))) short bf16x8;
typedef __attribute__((ext_vector_type(4))) float f32x4;

__device__ __forceinline__ unsigned short f2bf(float f) {
    union { float f; unsigned u; } v; v.f = f;
    unsigned u = v.u;
    unsigned r = (u + 0x7FFFu + ((u >> 16) & 1u)) >> 16;  // RNE
    return (unsigned short)r;
}

// ---------------------------------------------------------------------------
// Kernel 1: build fragment-major B: embF[e][kt][cb][lane][8] bf16, kt < 320
// ---------------------------------------------------------------------------
__global__ __launch_bounds__(256) void build_embF(
    const float* __restrict__ ec, const float* __restrict__ er,
    unsigned short* __restrict__ embF)
{
    const int t = blockIdx.x * 256 + threadIdx.x;
    const int perE = KTPAD * NCB * 64;                 // 163840
    if (t >= 2 * perE) return;
    const int e    = t / perE;
    const int rem  = t - e * perE;
    const int kt   = rem >> 9;
    const int rem2 = rem & 511;
    const int cb   = rem2 >> 6;
    const int lane = rem2 & 63;
    const int col  = cb * 16 + (lane & 15);
    const int k0   = kt * 32 + (lane >> 4) * 8;

    unsigned short o[8];
    if (k0 + 8 <= VDIM) {
        const float* src = (e ? er : ec) + (size_t)col * VDIM + k0;
        #pragma unroll
        for (int j = 0; j < 8; ++j) o[j] = f2bf(src[j]);
    } else {
        #pragma unroll
        for (int j = 0; j < 8; ++j) o[j] = 0;
    }
    *reinterpret_cast<bf16x8*>(embF + (size_t)t * 8) =
        *reinterpret_cast<const bf16x8*>(o);
}

// ---------------------------------------------------------------------------
// Shared GEMM core (R9 structure, verified): computes acc[8] for one
// (rb, s, kc) wave tile of 16 rows x 128 cols over 5 slabs of 8 kt.
// ---------------------------------------------------------------------------
#define GEMM_CORE_BODY                                                       \
    __shared__ short aLds[4][16][256];        /* 32 KB, wave-private */       \
    const int rb = blockIdx.x;                                                \
    const int s  = blockIdx.y;                                                \
    const int kc = blockIdx.z;                                                \
    const float* A = (s == 0) ? a0 : (s == 1 ? a1 : a2);                      \
    const int e = (s == 0) ? 0 : 1;                                           \
    const int tid  = threadIdx.x;                                             \
    const int lane = tid & 63;                                                \
    const int w    = tid >> 6;                                                \
    const int l15  = lane & 15;                                               \
    const int quad = lane >> 4;                                               \
    const int slab0 = kc * SLABS_PER_CHUNK;                                   \
    const int rbase = rb * 64 + w * 16;                                       \
    const float* arow0 = A + (size_t)rbase * VDIM;                            \
    const unsigned short* bbase =                                             \
        embF + (size_t)e * KTPAD * NCB * 512 + (size_t)lane * 8;              \
    f32x4 acc[8];                                                             \
    _Pragma("unroll")                                                         \
    for (int ct = 0; ct < 8; ++ct) acc[ct] = (f32x4){0.f, 0.f, 0.f, 0.f};     \
    f32x4 sreg[16];                                                           \
    GLA(slab0);                                                               \
    _Pragma("unroll 1")                                                       \
    for (int si = 0; si < SLABS_PER_CHUNK; ++si) {                            \
        CVTWRITE();                                                           \
        if (si + 1 < SLABS_PER_CHUNK) GLA(slab0 + si + 1);                    \
        const int skt = (slab0 + si) * 8;                                     \
        _Pragma("unroll")                                                     \
        for (int kts = 0; kts < 8; ++kts) {                                   \
            const unsigned short* bk = bbase + (size_t)(skt + kts) * (NCB * 512); \
            bf16x8 af = *reinterpret_cast<const bf16x8*>(                     \
                &aLds[w][l15][(kts * 32 + quad * 8) ^ ((l15 & 7) << 3)]);     \
            _Pragma("unroll")                                                 \
            for (int ct = 0; ct < 8; ++ct) {                                  \
                bf16x8 bq = *reinterpret_cast<const bf16x8*>(bk + ct * 512);  \
                acc[ct] = __builtin_amdgcn_mfma_f32_16x16x32_bf16(af, bq, acc[ct], 0, 0, 0); \
            }                                                                 \
        }                                                                     \
    }

#define GLA(SL) do {                                                   \
        int f_ = (SL) * 256 + lane * 4;                                \
        f_ = f_ > (VDIM - 4) ? (VDIM - 4) : f_;                        \
        _Pragma("unroll")                                              \
        for (int j = 0; j < 16; ++j)                                   \
            sreg[j] = *reinterpret_cast<const f32x4*>(                 \
                arow0 + (size_t)j * VDIM + f_);                        \
    } while (0)

#define CVTWRITE() do {                                                \
        _Pragma("unroll")                                              \
        for (int j = 0; j < 16; ++j) {                                 \
            union { unsigned u[2]; } p_;                               \
            asm("v_cvt_pk_bf16_f32 %0, %1, %2"                         \
                : "=v"(p_.u[0]) : "v"(sreg[j][0]), "v"(sreg[j][1]));   \
            asm("v_cvt_pk_bf16_f32 %0, %1, %2"                         \
                : "=v"(p_.u[1]) : "v"(sreg[j][2]), "v"(sreg[j][3]));   \
            int col_ = (lane * 4) ^ ((j & 7) << 3);                    \
            *reinterpret_cast<uint2*>(&aLds[w][j][col_]) =             \
                *reinterpret_cast<const uint2*>(p_.u);                 \
        }                                                              \
    } while (0)

// ---------------------------------------------------------------------------
// Kernel 2a (preferred): GEMM with PLAIN STORES to per-chunk partials
// reps8[kc][s][4096][128] f32 — ZERO atomics.
// ---------------------------------------------------------------------------
__global__ __launch_bounds__(256, 2) void gemm_rep_store(
    const float* __restrict__ a0, const float* __restrict__ a1,
    const float* __restrict__ a2,
    const unsigned short* __restrict__ embF,
    float* __restrict__ reps8)                // [8][3][4096][128] f32
{
    GEMM_CORE_BODY
    float* rp = reps8 + (((size_t)kc * 3 + s) * NROW + rbase) * DDIM;
    #pragma unroll
    for (int ct = 0; ct < 8; ++ct)
        #pragma unroll
        for (int r = 0; r < 4; ++r)
            rp[(size_t)(quad * 4 + r) * DDIM + ct * 16 + l15] = acc[ct][r];
}

// ---------------------------------------------------------------------------
// Kernel 2b (fallback, small ws): GEMM with atomicAdd into reps[3][4096][128]
// ---------------------------------------------------------------------------
__global__ __launch_bounds__(256, 2) void gemm_rep_atomic(
    const float* __restrict__ a0, const float* __restrict__ a1,
    const float* __restrict__ a2,
    const unsigned short* __restrict__ embF,
    float* __restrict__ reps)                 // [3][4096][128] f32 (zeroed)
{
    GEMM_CORE_BODY
    float* rp = reps + (size_t)s * NROW * DDIM + (size_t)rbase * DDIM;
    #pragma unroll
    for (int ct = 0; ct < 8; ++ct)
        #pragma unroll
        for (int r = 0; r < 4; ++r)
            atomicAdd(rp + (size_t)(quad * 4 + r) * DDIM + ct * 16 + l15,
                      acc[ct][r]);
}
#undef CVTWRITE
#undef GLA
#undef GEMM_CORE_BODY

// ---------------------------------------------------------------------------
// Kernel 3a: reduce 8 partial chunks + row dots + hinge loss. wave-per-row.
// ---------------------------------------------------------------------------
__global__ __launch_bounds__(256) void finalize8(
    const float* __restrict__ reps8, float* __restrict__ out)
{
    __shared__ float ls[4];
    const int wid  = threadIdx.x >> 6;
    const int lane = threadIdx.x & 63;
    const int row  = blockIdx.x * 4 + wid;

    float2 cs = {0.f, 0.f}, rs = {0.f, 0.f}, ns = {0.f, 0.f};
    #pragma unroll
    for (int kc = 0; kc < KSPLIT; ++kc) {
        const float* base = reps8 + ((size_t)kc * 3 * NROW + row) * DDIM + 2 * lane;
        const float2 cv = *reinterpret_cast<const float2*>(base);
        const float2 rv = *reinterpret_cast<const float2*>(base + (size_t)NROW * DDIM);
        const float2 nv = *reinterpret_cast<const float2*>(base + (size_t)2 * NROW * DDIM);
        cs.x += cv.x; cs.y += cv.y;
        rs.x += rv.x; rs.y += rv.y;
        ns.x += nv.x; ns.y += nv.y;
    }

    float fp = cs.x * rs.x + cs.y * rs.y;
    float fn = cs.x * ns.x + cs.y * ns.y;
    #pragma unroll
    for (int off = 32; off > 0; off >>= 1) {
        fp += __shfl_down(fp, off);
        fn += __shfl_down(fn, off);
    }
    if (lane == 0) {
        out[row]        = fp;
        out[NROW + row] = fn;
        float t = fn - fp + 0.5f;
        ls[wid] = t > 0.f ? t : 0.f;
    }
    __syncthreads();
    if (threadIdx.x == 0)
        atomicAdd(out + 2 * NROW, ls[0] + ls[1] + ls[2] + ls[3]);
}

// ---------------------------------------------------------------------------
// Kernel 3b: fallback finalize (reps already summed via atomics)
// ---------------------------------------------------------------------------
__global__ __launch_bounds__(256) void finalize1(
    const float* __restrict__ reps, float* __restrict__ out)
{
    __shared__ float ls[4];
    const int wid  = threadIdx.x >> 6;
    const int lane = threadIdx.x & 63;
    const int row  = blockIdx.x * 4 + wid;

    const float* c = reps + (size_t)row * DDIM + 2 * lane;
    const float2 cv = *reinterpret_cast<const float2*>(c);
    const float2 rv = *reinterpret_cast<const float2*>(c + (size_t)NROW * DDIM);
    const float2 nv = *reinterpret_cast<const float2*>(c + (size_t)2 * NROW * DDIM);

    float fp = cv.x * rv.x + cv.y * rv.y;
    float fn = cv.x * nv.x + cv.y * nv.y;
    #pragma unroll
    for (int off = 32; off > 0; off >>= 1) {
        fp += __shfl_down(fp, off);
        fn += __shfl_down(fn, off);
    }
    if (lane == 0) {
        out[row]        = fp;
        out[NROW + row] = fn;
        float t = fn - fp + 0.5f;
        ls[wid] = t > 0.f ? t : 0.f;
    }
    __syncthreads();
    if (threadIdx.x == 0)
        atomicAdd(out + 2 * NROW, ls[0] + ls[1] + ls[2] + ls[3]);
}

// ---------------------------------------------------------------------------
extern "C" void kernel_launch(void* const* d_in, const int* in_sizes, int n_in,
                              void* d_out, int out_size, void* d_ws, size_t ws_size,
                              hipStream_t stream)
{
    const float* cb  = (const float*)d_in[0];
    const float* rbb = (const float*)d_in[1];
    const float* nb  = (const float*)d_in[2];
    const float* ce  = (const float*)d_in[3];
    const float* re  = (const float*)d_in[4];
    float* out = (float*)d_out;

    unsigned short* embF = (unsigned short*)d_ws;
    const size_t embBytes   = (size_t)2 * KTPAD * NCB * 512 * sizeof(unsigned short); // 5.24 MB
    const size_t reps8Bytes = (size_t)KSPLIT * 3 * NROW * DDIM * sizeof(float);       // 50.3 MB
    const size_t repsBytes  = (size_t)3 * NROW * DDIM * sizeof(float);                // 6.29 MB

    build_embF<<<dim3((2 * KTPAD * NCB * 64 + 255) / 256), dim3(256), 0, stream>>>(ce, re, embF);
    hipMemsetAsync(out + 2 * NROW, 0, sizeof(float), stream);

    if (ws_size >= embBytes + reps8Bytes) {
        // preferred path: plain-store partials, zero atomics in GEMM
        float* reps8 = (float*)((char*)d_ws + embBytes);
        gemm_rep_store<<<dim3(NROW / 64, 3, KSPLIT), dim3(256), 0, stream>>>(
            cb, rbb, nb, embF, reps8);
        finalize8<<<dim3(NROW / 4), dim3(256), 0, stream>>>(reps8, out);
    } else {
        // fallback: atomic accumulation (R9 behavior)
        float* reps = (float*)((char*)d_ws + embBytes);
        hipMemsetAsync(reps, 0, repsBytes, stream);
        gemm_rep_atomic<<<dim3(NROW / 64, 3, KSPLIT), dim3(256), 0, stream>>>(
            cb, rbb, nb, embF, reps);
        finalize1<<<dim3(NROW / 4), dim3(256), 0, stream>>>(reps, out);
    }
}